// Round 15
// baseline (225.537 us; speedup 1.0000x reference)
//
#include <hip/hip_runtime.h>

#define SELU_SCALE 1.0507009873554805f
#define SELU_ALPHA 1.6732632423543772f

typedef __attribute__((ext_vector_type(8))) short short8;
typedef __attribute__((ext_vector_type(4))) float f32x4;

#define BCAP 10240  // entries per 512-node bucket (mean ~8704)

static __device__ __forceinline__ float leaky02(float v) {
  return v > 0.0f ? v : 0.2f * v;
}

static __device__ __forceinline__ ushort f2bf(float f) {
  uint b = __float_as_uint(f);
  return (ushort)((b + 0x7fffu + ((b >> 16) & 1u)) >> 16);
}
static __device__ __forceinline__ float bf2f(ushort u) {
  return __uint_as_float(((uint)u) << 16);
}

static __device__ __forceinline__ float selu_f(float y) {
  return y > 0.f ? SELU_SCALE * y : SELU_SCALE * SELU_ALPHA * (__expf(y) - 1.f);
}

// X-row loaders (fp32 or bf16 source)
static __device__ __forceinline__ void load8(const float* p, float* xv, bool ok) {
  float4 xa = make_float4(0.f, 0.f, 0.f, 0.f), xb = xa;
  if (ok) {
    xa = *(const float4*)p;
    xb = *(const float4*)(p + 4);
  }
  xv[0] = xa.x; xv[1] = xa.y; xv[2] = xa.z; xv[3] = xa.w;
  xv[4] = xb.x; xv[5] = xb.y; xv[6] = xb.z; xv[7] = xb.w;
}
static __device__ __forceinline__ void load8(const ushort* p, float* xv, bool ok) {
  ushort4 ua = make_ushort4(0, 0, 0, 0), ub = ua;
  if (ok) {
    ua = *(const ushort4*)p;
    ub = *(const ushort4*)(p + 4);
  }
  xv[0] = bf2f(ua.x); xv[1] = bf2f(ua.y); xv[2] = bf2f(ua.z); xv[3] = bf2f(ua.w);
  xv[4] = bf2f(ub.x); xv[5] = bf2f(ub.y); xv[6] = bf2f(ub.z); xv[7] = bf2f(ub.w);
}

// ---------------- prep: edge bucketing (blocks < nbb) + W pack (blocks >= nbb) --------
// bucket id = dst>>9 (512-node buckets); entry = (src<<9)|(dst&511).
// NOTE: gcur/stats are zeroed by hipMemsetAsync BEFORE this launch (zeroing in-launch
// would race with bucket's gcur atomics).
__global__ __launch_bounds__(256) void prep_kernel(
    const int* __restrict__ ei, int* __restrict__ gcur, uint* __restrict__ bucket,
    const float* __restrict__ W1, const float* __restrict__ W2,
    ushort* __restrict__ Wp1, ushort* __restrict__ Wp2,
    int nE, int EA, int NB, int nbb) {
  int tid = threadIdx.x;
  if (blockIdx.x >= nbb) {
    int idx = (blockIdx.x - nbb) * 256 + tid;  // 0..32767
    const float* W = (idx < 16384) ? W1 : W2;
    ushort* Wp = (idx < 16384) ? Wp1 : Wp2;
    int t = idx & 16383;
    int b = t & 7, i = (t >> 3) & 15, g = (t >> 7) & 3, kt = (t >> 9) & 3, ct = t >> 11;
    int k = kt * 32 + g * 8 + b, col = ct * 16 + i;
    Wp[t] = f2bf(W[k * 128 + col]);
    return;
  }
  __shared__ int lcnt[128];
  __shared__ int lbase[128];
  if (tid < 128) lcnt[tid] = 0;
  __syncthreads();
  int e0 = blockIdx.x * 1024;
  uint ent[4];
  int bk[4], lp[4];
#pragma unroll
  for (int j = 0; j < 4; ++j) {
    int e = e0 + j * 256 + tid;
    bk[j] = -1;
    if (e < EA) {
      int src, dst;
      if (e < nE) {
        src = ei[e];
        dst = ei[nE + e];
      } else {
        src = dst = e - nE;
      }
      bk[j] = dst >> 9;
      ent[j] = ((uint)src << 9) | (uint)(dst & 511);
      lp[j] = atomicAdd(&lcnt[bk[j]], 1);
    }
  }
  __syncthreads();
  if (tid < NB && lcnt[tid] > 0) lbase[tid] = atomicAdd(&gcur[tid], lcnt[tid]);
  __syncthreads();
#pragma unroll
  for (int j = 0; j < 4; ++j) {
    if (bk[j] >= 0) bucket[(size_t)bk[j] * BCAP + lbase[bk[j]] + lp[j]] = ent[j];
  }
}

// ---------------- GEMM body (64 rows/block, 8 ct per wave) ----------------
template <int HEADS, bool BN, typename XT>
static __device__ __forceinline__ void gemm_body(
    int blk, const XT* __restrict__ X, const ushort* __restrict__ Wp,
    ushort* __restrict__ H, const float* __restrict__ asr, const float* __restrict__ adt,
    float* __restrict__ ssrc, float* __restrict__ sdst, int n,
    const float* __restrict__ stats, const float* __restrict__ gamma,
    const float* __restrict__ beta) {
  __shared__ float sc[128], sh[128];
  if (BN) {
    int t = threadIdx.x;
    if (t < 128) {
      float invN = 1.0f / (float)n;
      float mu = stats[t] * invN;
      float var = stats[128 + t] * invN - mu * mu;
      float rs = rsqrtf(var + 1e-5f);
      float s = gamma[t] * rs;
      sc[t] = s;
      sh[t] = beta[t] - s * mu;
    }
    __syncthreads();
  }
  const int tid = threadIdx.x;
  const int w = tid >> 6, l = tid & 63;
  const int lj = l & 15, lg = l >> 4;
  const int row = blk * 64 + w * 16 + lj;
  const bool rowok = row < n;
  const XT* xrow = X + (size_t)row * 128;

  f32x4 acc[8];
#pragma unroll
  for (int ct = 0; ct < 8; ++ct) acc[ct] = (f32x4){0.f, 0.f, 0.f, 0.f};

#pragma unroll
  for (int kt = 0; kt < 4; ++kt) {
    const int k0 = kt * 32 + lg * 8;
    float xv[8];
    load8(xrow + k0, xv, rowok);
    if (BN) {
#pragma unroll
      for (int b = 0; b < 8; ++b) xv[b] = selu_f(xv[b] * sc[k0 + b] + sh[k0 + b]);
    }
    short8 bx;
#pragma unroll
    for (int b = 0; b < 8; ++b) bx[b] = (short)f2bf(xv[b]);
#pragma unroll
    for (int ct = 0; ct < 8; ++ct) {
      short8 af = *(const short8*)(Wp + ((((ct * 4 + kt) * 4 + lg) * 16 + lj) << 3));
      acc[ct] = __builtin_amdgcn_mfma_f32_16x16x32_bf16(af, bx, acc[ct], 0, 0, 0);
    }
  }

  if (rowok) {
#pragma unroll
    for (int ct = 0; ct < 8; ++ct) {
      ushort4 h4;
      h4.x = f2bf(acc[ct][0]);
      h4.y = f2bf(acc[ct][1]);
      h4.z = f2bf(acc[ct][2]);
      h4.w = f2bf(acc[ct][3]);
      *(ushort4*)&H[(size_t)row * 128 + ct * 16 + lg * 4] = h4;
    }
  }

  if (HEADS == 8) {
    float ps[8], pd[8];
#pragma unroll
    for (int ct = 0; ct < 8; ++ct) {
      float4 av = *(const float4*)&asr[ct * 16 + lg * 4];
      float4 dv = *(const float4*)&adt[ct * 16 + lg * 4];
      ps[ct] = acc[ct][0] * av.x + acc[ct][1] * av.y + acc[ct][2] * av.z + acc[ct][3] * av.w;
      pd[ct] = acc[ct][0] * dv.x + acc[ct][1] * dv.y + acc[ct][2] * dv.z + acc[ct][3] * dv.w;
      ps[ct] += __shfl_xor(ps[ct], 16);
      ps[ct] += __shfl_xor(ps[ct], 32);
      pd[ct] += __shfl_xor(pd[ct], 16);
      pd[ct] += __shfl_xor(pd[ct], 32);
    }
    if (lg == 0 && rowok) {
      *(float4*)&ssrc[(size_t)row * 8] = make_float4(ps[0], ps[1], ps[2], ps[3]);
      *(float4*)&ssrc[(size_t)row * 8 + 4] = make_float4(ps[4], ps[5], ps[6], ps[7]);
      *(float4*)&sdst[(size_t)row * 8] = make_float4(pd[0], pd[1], pd[2], pd[3]);
      *(float4*)&sdst[(size_t)row * 8 + 4] = make_float4(pd[4], pd[5], pd[6], pd[7]);
    }
  } else {
    float ps = 0.f, pd = 0.f;
#pragma unroll
    for (int ct = 0; ct < 8; ++ct) {
      float4 av = *(const float4*)&asr[ct * 16 + lg * 4];
      float4 dv = *(const float4*)&adt[ct * 16 + lg * 4];
      ps += acc[ct][0] * av.x + acc[ct][1] * av.y + acc[ct][2] * av.z + acc[ct][3] * av.w;
      pd += acc[ct][0] * dv.x + acc[ct][1] * dv.y + acc[ct][2] * dv.z + acc[ct][3] * dv.w;
    }
    ps += __shfl_xor(ps, 16);
    ps += __shfl_xor(ps, 32);
    pd += __shfl_xor(pd, 16);
    pd += __shfl_xor(pd, 32);
    if (lg == 0 && rowok) {
      ssrc[row] = ps;
      sdst[row] = pd;
    }
  }
}

// ---------------- CSR build body (256 threads, one 512-node bucket) ----------------
static __device__ __forceinline__ void csr_body(int b, const int* __restrict__ gcur,
                                                const uint* __restrict__ bucket,
                                                int* __restrict__ offs,
                                                int* __restrict__ csr, int n, int NB) {
  __shared__ int ldeg[512];
  __shared__ int lwsum[4];
  __shared__ int partial[2];
  int tid = threadIdx.x;
  int lane = tid & 63, w = tid >> 6;
  if (tid < 128) {
    int v = (tid < b) ? gcur[tid] : 0;
#pragma unroll
    for (int s = 1; s < 64; s <<= 1) v += __shfl_xor(v, s);
    if (lane == 0) partial[tid >> 6] = v;
  }
  ldeg[tid] = 0;
  ldeg[tid + 256] = 0;
  __syncthreads();
  int base = partial[0] + partial[1];
  int cnt = gcur[b];
  const uint* bb = bucket + (size_t)b * BCAP;
  for (int k = tid; k < cnt; k += 256) atomicAdd(&ldeg[bb[k] & 511], 1);
  __syncthreads();
  int v0 = ldeg[tid * 2], v1 = ldeg[tid * 2 + 1];
  int t = v0 + v1;
  int x = t;
#pragma unroll
  for (int s = 1; s < 64; s <<= 1) {
    int tt = __shfl_up(x, s);
    if (lane >= s) x += tt;
  }
  if (lane == 63) lwsum[w] = x;
  __syncthreads();
  if (tid == 0) {
    int s = 0;
#pragma unroll
    for (int j = 0; j < 4; ++j) {
      int tmp = lwsum[j];
      lwsum[j] = s;
      s += tmp;
    }
  }
  __syncthreads();
  int excl = x - t + lwsum[w];
  int node0 = b * 512 + tid * 2;
  if (node0 < n) offs[node0] = base + excl;
  if (node0 + 1 < n) offs[node0 + 1] = base + excl + v0;
  if (b == NB - 1 && tid == 0) offs[n] = base + cnt;
  __syncthreads();
  ldeg[tid * 2] = excl;
  ldeg[tid * 2 + 1] = excl + v0;
  __syncthreads();
  for (int k = tid; k < cnt; k += 256) {
    uint e = bb[k];
    int pos = atomicAdd(&ldeg[e & 511], 1);
    csr[base + pos] = (int)(e >> 9);
  }
}

// ---------------- fused: GEMM1 (blocks < gb) + CSR build (blocks >= gb) ----------
__global__ __launch_bounds__(256) void gemm1csr_kernel(
    const float* __restrict__ X, const ushort* __restrict__ Wp, ushort* __restrict__ H,
    const float* __restrict__ asr, const float* __restrict__ adt,
    float* __restrict__ ssrc, float* __restrict__ sdst, int n,
    const int* __restrict__ gcur, const uint* __restrict__ bucket,
    int* __restrict__ offs, int* __restrict__ csr, int NB, int gb) {
  if (blockIdx.x < gb) {
    gemm_body<8, false, float>(blockIdx.x, X, Wp, H, asr, adt, ssrc, sdst, n,
                               nullptr, nullptr, nullptr);
  } else {
    csr_body(blockIdx.x - gb, gcur, bucket, offs, csr, n, NB);
  }
}

// ---------------- GEMM2 standalone (bf16 X, BN fused) ----------------
__global__ __launch_bounds__(256) void gemm2_kernel(
    const ushort* __restrict__ X, const ushort* __restrict__ Wp, ushort* __restrict__ H,
    const float* __restrict__ asr, const float* __restrict__ adt,
    float* __restrict__ ssrc, float* __restrict__ sdst, int n,
    const float* __restrict__ stats, const float* __restrict__ gamma,
    const float* __restrict__ beta) {
  gemm_body<1, true, ushort>(blockIdx.x, X, Wp, H, asr, adt, ssrc, sdst, n,
                             stats, gamma, beta);
}

// -------- agg layer 1: quarter-waves (16 lanes/quarter), 8 ch/lane, bf16 out ----------
// All accumulators NAMED SCALARS (R12: arrays spill). No fused stats (R12: atomic storm).
__global__ __launch_bounds__(256) void agg1_kernel(const ushort* __restrict__ h1,
                                                   const int* __restrict__ csr,
                                                   const int* __restrict__ offs,
                                                   const float* __restrict__ ssrc,
                                                   const float* __restrict__ sdst,
                                                   const float* __restrict__ bias,
                                                   ushort* __restrict__ outb, int nN) {
  int wid = (blockIdx.x * blockDim.x + threadIdx.x) >> 6;
  int lane = threadIdx.x & 63;
  int q = lane >> 4, ll = lane & 15;
  if (wid >= nN) return;
  int c = ll * 8;   // 8 channels per lane
  int h = ll >> 1;  // head = c/16
  float sd = sdst[wid * 8 + h];
  int beg = offs[wid];
  int deg = offs[wid + 1] - beg;
  float b0 = 0.f, b1 = 0.f, b2 = 0.f, b3 = 0.f;
  float b4 = 0.f, b5 = 0.f, b6 = 0.f, b7 = 0.f, den = 0.f;
  int i = q;
  for (; i + 4 < deg; i += 8) {
    int s0 = csr[beg + i];
    int s1 = csr[beg + i + 4];
    float e0 = ssrc[s0 * 8 + h];
    float e1 = ssrc[s1 * 8 + h];
    short8 u0 = *(const short8*)&h1[(size_t)s0 * 128 + c];
    short8 u1 = *(const short8*)&h1[(size_t)s1 * 128 + c];
    float A0 = __expf(leaky02(e0 + sd));
    float A1 = __expf(leaky02(e1 + sd));
    b0 += A0 * bf2f((ushort)u0[0]) + A1 * bf2f((ushort)u1[0]);
    b1 += A0 * bf2f((ushort)u0[1]) + A1 * bf2f((ushort)u1[1]);
    b2 += A0 * bf2f((ushort)u0[2]) + A1 * bf2f((ushort)u1[2]);
    b3 += A0 * bf2f((ushort)u0[3]) + A1 * bf2f((ushort)u1[3]);
    b4 += A0 * bf2f((ushort)u0[4]) + A1 * bf2f((ushort)u1[4]);
    b5 += A0 * bf2f((ushort)u0[5]) + A1 * bf2f((ushort)u1[5]);
    b6 += A0 * bf2f((ushort)u0[6]) + A1 * bf2f((ushort)u1[6]);
    b7 += A0 * bf2f((ushort)u0[7]) + A1 * bf2f((ushort)u1[7]);
    den += A0 + A1;
  }
  if (i < deg) {
    int s0 = csr[beg + i];
    float e0 = ssrc[s0 * 8 + h];
    short8 u0 = *(const short8*)&h1[(size_t)s0 * 128 + c];
    float A0 = __expf(leaky02(e0 + sd));
    b0 += A0 * bf2f((ushort)u0[0]);
    b1 += A0 * bf2f((ushort)u0[1]);
    b2 += A0 * bf2f((ushort)u0[2]);
    b3 += A0 * bf2f((ushort)u0[3]);
    b4 += A0 * bf2f((ushort)u0[4]);
    b5 += A0 * bf2f((ushort)u0[5]);
    b6 += A0 * bf2f((ushort)u0[6]);
    b7 += A0 * bf2f((ushort)u0[7]);
    den += A0;
  }
  b0 += __shfl_xor(b0, 16); b0 += __shfl_xor(b0, 32);
  b1 += __shfl_xor(b1, 16); b1 += __shfl_xor(b1, 32);
  b2 += __shfl_xor(b2, 16); b2 += __shfl_xor(b2, 32);
  b3 += __shfl_xor(b3, 16); b3 += __shfl_xor(b3, 32);
  b4 += __shfl_xor(b4, 16); b4 += __shfl_xor(b4, 32);
  b5 += __shfl_xor(b5, 16); b5 += __shfl_xor(b5, 32);
  b6 += __shfl_xor(b6, 16); b6 += __shfl_xor(b6, 32);
  b7 += __shfl_xor(b7, 16); b7 += __shfl_xor(b7, 32);
  den += __shfl_xor(den, 16); den += __shfl_xor(den, 32);
  if (q == 0) {
    float invd = 1.0f / (den + 1e-16f);
    float4 bv0 = *(const float4*)&bias[c];
    float4 bv1 = *(const float4*)&bias[c + 4];
    short8 o;
    o[0] = (short)f2bf(b0 * invd + bv0.x);
    o[1] = (short)f2bf(b1 * invd + bv0.y);
    o[2] = (short)f2bf(b2 * invd + bv0.z);
    o[3] = (short)f2bf(b3 * invd + bv0.w);
    o[4] = (short)f2bf(b4 * invd + bv1.x);
    o[5] = (short)f2bf(b5 * invd + bv1.y);
    o[6] = (short)f2bf(b6 * invd + bv1.z);
    o[7] = (short)f2bf(b7 * invd + bv1.w);
    *(short8*)&outb[(size_t)wid * 128 + c] = o;
  }
}

// -------- agg layer 2: quarter-waves, 8 ch/lane, bf16 out (pre-BN rounding) ----------
__global__ __launch_bounds__(256) void agg2_kernel(const ushort* __restrict__ h2,
                                                   const int* __restrict__ csr,
                                                   const int* __restrict__ offs,
                                                   const float* __restrict__ ssrc,
                                                   const float* __restrict__ sdst,
                                                   const float* __restrict__ bias,
                                                   ushort* __restrict__ outb, int nN) {
  int wid = (blockIdx.x * blockDim.x + threadIdx.x) >> 6;
  int lane = threadIdx.x & 63;
  int q = lane >> 4, ll = lane & 15;
  if (wid >= nN) return;
  int c = ll * 8;
  float sd = sdst[wid];
  int beg = offs[wid];
  int deg = offs[wid + 1] - beg;
  float b0 = 0.f, b1 = 0.f, b2 = 0.f, b3 = 0.f;
  float b4 = 0.f, b5 = 0.f, b6 = 0.f, b7 = 0.f, den = 0.f;
  int i = q;
  for (; i + 4 < deg; i += 8) {
    int s0 = csr[beg + i];
    int s1 = csr[beg + i + 4];
    float e0 = ssrc[s0];
    float e1 = ssrc[s1];
    short8 u0 = *(const short8*)&h2[(size_t)s0 * 128 + c];
    short8 u1 = *(const short8*)&h2[(size_t)s1 * 128 + c];
    float A0 = __expf(leaky02(e0 + sd));
    float A1 = __expf(leaky02(e1 + sd));
    b0 += A0 * bf2f((ushort)u0[0]) + A1 * bf2f((ushort)u1[0]);
    b1 += A0 * bf2f((ushort)u0[1]) + A1 * bf2f((ushort)u1[1]);
    b2 += A0 * bf2f((ushort)u0[2]) + A1 * bf2f((ushort)u1[2]);
    b3 += A0 * bf2f((ushort)u0[3]) + A1 * bf2f((ushort)u1[3]);
    b4 += A0 * bf2f((ushort)u0[4]) + A1 * bf2f((ushort)u1[4]);
    b5 += A0 * bf2f((ushort)u0[5]) + A1 * bf2f((ushort)u1[5]);
    b6 += A0 * bf2f((ushort)u0[6]) + A1 * bf2f((ushort)u1[6]);
    b7 += A0 * bf2f((ushort)u0[7]) + A1 * bf2f((ushort)u1[7]);
    den += A0 + A1;
  }
  if (i < deg) {
    int s0 = csr[beg + i];
    float e0 = ssrc[s0];
    short8 u0 = *(const short8*)&h2[(size_t)s0 * 128 + c];
    float A0 = __expf(leaky02(e0 + sd));
    b0 += A0 * bf2f((ushort)u0[0]);
    b1 += A0 * bf2f((ushort)u0[1]);
    b2 += A0 * bf2f((ushort)u0[2]);
    b3 += A0 * bf2f((ushort)u0[3]);
    b4 += A0 * bf2f((ushort)u0[4]);
    b5 += A0 * bf2f((ushort)u0[5]);
    b6 += A0 * bf2f((ushort)u0[6]);
    b7 += A0 * bf2f((ushort)u0[7]);
    den += A0;
  }
  b0 += __shfl_xor(b0, 16); b0 += __shfl_xor(b0, 32);
  b1 += __shfl_xor(b1, 16); b1 += __shfl_xor(b1, 32);
  b2 += __shfl_xor(b2, 16); b2 += __shfl_xor(b2, 32);
  b3 += __shfl_xor(b3, 16); b3 += __shfl_xor(b3, 32);
  b4 += __shfl_xor(b4, 16); b4 += __shfl_xor(b4, 32);
  b5 += __shfl_xor(b5, 16); b5 += __shfl_xor(b5, 32);
  b6 += __shfl_xor(b6, 16); b6 += __shfl_xor(b6, 32);
  b7 += __shfl_xor(b7, 16); b7 += __shfl_xor(b7, 32);
  den += __shfl_xor(den, 16); den += __shfl_xor(den, 32);
  if (q == 0) {
    float invd = 1.0f / (den + 1e-16f);
    float4 bv0 = *(const float4*)&bias[c];
    float4 bv1 = *(const float4*)&bias[c + 4];
    short8 o;
    o[0] = (short)f2bf(b0 * invd + bv0.x);
    o[1] = (short)f2bf(b1 * invd + bv0.y);
    o[2] = (short)f2bf(b2 * invd + bv0.z);
    o[3] = (short)f2bf(b3 * invd + bv0.w);
    o[4] = (short)f2bf(b4 * invd + bv1.x);
    o[5] = (short)f2bf(b5 * invd + bv1.y);
    o[6] = (short)f2bf(b6 * invd + bv1.z);
    o[7] = (short)f2bf(b7 * invd + bv1.w);
    *(short8*)&outb[(size_t)wid * 128 + c] = o;
  }
}

// ---------------- column stats (sum, sumsq): bf16 input ----------------
__global__ __launch_bounds__(256) void stats_bf16_kernel(const ushort* __restrict__ X,
                                                         float* __restrict__ stats, int n) {
  __shared__ float red[256];
  int tid = threadIdx.x;
  int c = tid & 127;
  int half = tid >> 7;
  float s = 0.f, sq = 0.f;
  int rbeg = (int)blockIdx.x * 64 + half;
  int rend = min((int)(blockIdx.x + 1) * 64, n);
#pragma unroll 4
  for (int r = rbeg; r < rend; r += 2) {
    float v = bf2f(X[(size_t)r * 128 + c]);
    s += v;
    sq += v * v;
  }
  red[tid] = s;
  __syncthreads();
  float s2 = (half == 0) ? s + red[tid + 128] : 0.f;
  __syncthreads();
  red[tid] = sq;
  __syncthreads();
  if (half == 0) {
    float sq2 = sq + red[tid + 128];
    atomicAdd(&stats[c], s2);
    atomicAdd(&stats[128 + c], sq2);
  }
}

// ---------------- BatchNorm (batch stats, biased var) + SELU: bf16 in, fp32 out -------
__global__ __launch_bounds__(256) void bnselu_bf16_kernel(const ushort* __restrict__ X,
                                                          const float* __restrict__ stats,
                                                          const float* __restrict__ gamma,
                                                          const float* __restrict__ beta,
                                                          float* __restrict__ Y, int n) {
  int gid = blockIdx.x * blockDim.x + threadIdx.x;
  if (gid >= n * 32) return;
  int c = (gid & 31) * 4;
  int r = gid >> 5;
  float invN = 1.0f / (float)n;
  ushort4 u = *(const ushort4*)&X[(size_t)r * 128 + c];
  float xv[4] = {bf2f(u.x), bf2f(u.y), bf2f(u.z), bf2f(u.w)};
  float o[4];
#pragma unroll
  for (int j = 0; j < 4; ++j) {
    float mu = stats[c + j] * invN;
    float var = stats[128 + c + j] * invN - mu * mu;
    float rs = rsqrtf(var + 1e-5f);
    float y = gamma[c + j] * ((xv[j] - mu) * rs) + beta[c + j];
    o[j] = selu_f(y);
  }
  *(float4*)&Y[(size_t)r * 128 + c] = make_float4(o[0], o[1], o[2], o[3]);
}

extern "C" void kernel_launch(void* const* d_in, const int* in_sizes, int n_in,
                              void* d_out, int out_size, void* d_ws, size_t ws_size,
                              hipStream_t stream) {
  const float* x   = (const float*)d_in[0];
  const int*   ei  = (const int*)d_in[1];
  // d_in[2] = edge_attr: unused (edge_dim=None)
  const float* W1  = (const float*)d_in[3];
  const float* as1 = (const float*)d_in[4];
  const float* ad1 = (const float*)d_in[5];
  const float* b1  = (const float*)d_in[6];
  const float* g1  = (const float*)d_in[7];
  const float* be1 = (const float*)d_in[8];
  const float* W2  = (const float*)d_in[9];
  const float* as2 = (const float*)d_in[10];
  const float* ad2 = (const float*)d_in[11];
  const float* b2  = (const float*)d_in[12];
  const float* g2  = (const float*)d_in[13];
  const float* be2 = (const float*)d_in[14];
  float* out = (float*)d_out;

  const int n  = in_sizes[0] / 128;   // 50000
  const int nE = in_sizes[1] / 2;     // 800000
  const int EA = nE + n;              // 850000
  const int NB = (n + 511) >> 9;      // 98 dst buckets (512 nodes each)
  const int nbb = (EA + 1023) / 1024; // bucket blocks
  const int gb = (n + 63) / 64;       // gemm blocks

  float* ws = (float*)d_ws;
  size_t o = 0;
  ushort* Bf = (ushort*)(ws + o); o += (size_t)n * 64;  // bf16: agg out / BN+gemm2 in
  ushort* H = (ushort*)(ws + o); o += (size_t)n * 64;   // bf16 h (gather table, reused)
  float* ssrc1 = ws + o;  o += (size_t)n * 8;
  float* sdst1 = ws + o;  o += (size_t)n * 8;
  float* ssrc2 = ws + o;  o += n;
  float* sdst2 = ws + o;  o += n;
  ushort* Wp1 = (ushort*)(ws + o); o += 8192;     // 16384 bf16
  ushort* Wp2 = (ushort*)(ws + o); o += 8192;
  // ---- zero region start ----
  float* zbase = ws + o;
  float* stats1 = ws + o; o += 256;
  float* stats2 = ws + o; o += 256;
  int* gcur = (int*)(ws + o); o += 128;
  size_t zwords = (size_t)((ws + o) - zbase);
  // ---- zero region end ----
  int* offs = (int*)(ws + o); o += (size_t)n + 1;
  int* csr  = (int*)(ws + o); o += EA;
  uint* bucket = (uint*)(ws + o); o += (size_t)NB * BCAP;

  hipMemsetAsync(zbase, 0, zwords * sizeof(float), stream);

  // prep: edge bucketing ∥ W pack (both independent of everything else)
  prep_kernel<<<nbb + 128, 256, 0, stream>>>(ei, gcur, bucket, W1, W2, Wp1, Wp2,
                                             nE, EA, NB, nbb);

  // ---- layer 1 GEMM (+ fused scores) overlapped with CSR build ----
  gemm1csr_kernel<<<gb + NB, 256, 0, stream>>>(
      x, Wp1, H, as1, ad1, ssrc1, sdst1, n, gcur, bucket, offs, csr, NB, gb);

  agg1_kernel<<<(n + 3) / 4, 256, 0, stream>>>(H, csr, offs, ssrc1, sdst1, b1, Bf, n);
  stats_bf16_kernel<<<(n + 63) / 64, 256, 0, stream>>>(Bf, stats1, n);

  // ---- layer 2 (BN+SELU fused into GEMM2 X load; GEMM + fused scores) ----
  gemm2_kernel<<<gb, 256, 0, stream>>>(
      Bf, Wp2, H, as2, ad2, ssrc2, sdst2, n, stats1, g1, be1);
  agg2_kernel<<<(n + 3) / 4, 256, 0, stream>>>(H, csr, offs, ssrc2, sdst2, b2, Bf, n);
  stats_bf16_kernel<<<(n + 63) / 64, 256, 0, stream>>>(Bf, stats2, n);
  bnselu_bf16_kernel<<<(n * 32 + 255) / 256, 256, 0, stream>>>(Bf, stats2, g2, be2, out, n);
}

// Round 16
// 215.050 us; speedup vs baseline: 1.0488x; 1.0488x over previous
//
#include <hip/hip_runtime.h>

#define SELU_SCALE 1.0507009873554805f
#define SELU_ALPHA 1.6732632423543772f

typedef __attribute__((ext_vector_type(8))) short short8;
typedef __attribute__((ext_vector_type(4))) float f32x4;

#define BCAP 10240  // entries per 512-node bucket (mean ~8704)

static __device__ __forceinline__ float leaky02(float v) {
  return v > 0.0f ? v : 0.2f * v;
}

static __device__ __forceinline__ ushort f2bf(float f) {
  uint b = __float_as_uint(f);
  return (ushort)((b + 0x7fffu + ((b >> 16) & 1u)) >> 16);
}
static __device__ __forceinline__ float bf2f(ushort u) {
  return __uint_as_float(((uint)u) << 16);
}

static __device__ __forceinline__ float selu_f(float y) {
  return y > 0.f ? SELU_SCALE * y : SELU_SCALE * SELU_ALPHA * (__expf(y) - 1.f);
}

// X-row loaders (fp32 or bf16 source)
static __device__ __forceinline__ void load8(const float* p, float* xv, bool ok) {
  float4 xa = make_float4(0.f, 0.f, 0.f, 0.f), xb = xa;
  if (ok) {
    xa = *(const float4*)p;
    xb = *(const float4*)(p + 4);
  }
  xv[0] = xa.x; xv[1] = xa.y; xv[2] = xa.z; xv[3] = xa.w;
  xv[4] = xb.x; xv[5] = xb.y; xv[6] = xb.z; xv[7] = xb.w;
}
static __device__ __forceinline__ void load8(const ushort* p, float* xv, bool ok) {
  ushort4 ua = make_ushort4(0, 0, 0, 0), ub = ua;
  if (ok) {
    ua = *(const ushort4*)p;
    ub = *(const ushort4*)(p + 4);
  }
  xv[0] = bf2f(ua.x); xv[1] = bf2f(ua.y); xv[2] = bf2f(ua.z); xv[3] = bf2f(ua.w);
  xv[4] = bf2f(ub.x); xv[5] = bf2f(ub.y); xv[6] = bf2f(ub.z); xv[7] = bf2f(ub.w);
}

// ---------------- W pack + workspace zeroing ----------------
__global__ __launch_bounds__(256) void pack_kernel(const float* __restrict__ W1,
                                                   const float* __restrict__ W2,
                                                   ushort* __restrict__ Wp1,
                                                   ushort* __restrict__ Wp2,
                                                   float* __restrict__ zbase, int zwords) {
  if (blockIdx.x == 128) {
    for (int i = threadIdx.x; i < zwords; i += 256) zbase[i] = 0.f;
    return;
  }
  int idx = blockIdx.x * 256 + threadIdx.x;  // 0..32767
  const float* W = (idx < 16384) ? W1 : W2;
  ushort* Wp = (idx < 16384) ? Wp1 : Wp2;
  int t = idx & 16383;
  int b = t & 7, i = (t >> 3) & 15, g = (t >> 7) & 3, kt = (t >> 9) & 3, ct = t >> 11;
  int k = kt * 32 + g * 8 + b, col = ct * 16 + i;
  Wp[t] = f2bf(W[k * 128 + col]);
}

// ---------------- GEMM body (64 rows/block, 8 ct per wave) ----------------
template <int HEADS, bool BN, typename XT>
static __device__ __forceinline__ void gemm_body(
    int blk, const XT* __restrict__ X, const ushort* __restrict__ Wp,
    ushort* __restrict__ H, const float* __restrict__ asr, const float* __restrict__ adt,
    float* __restrict__ ssrc, float* __restrict__ sdst, int n,
    const float* __restrict__ stats, const float* __restrict__ gamma,
    const float* __restrict__ beta) {
  __shared__ float sc[128], sh[128];
  if (BN) {
    int t = threadIdx.x;
    if (t < 128) {
      float invN = 1.0f / (float)n;
      float mu = stats[t] * invN;
      float var = stats[128 + t] * invN - mu * mu;
      float rs = rsqrtf(var + 1e-5f);
      float s = gamma[t] * rs;
      sc[t] = s;
      sh[t] = beta[t] - s * mu;
    }
    __syncthreads();
  }
  const int tid = threadIdx.x;
  const int w = tid >> 6, l = tid & 63;
  const int lj = l & 15, lg = l >> 4;
  const int row = blk * 64 + w * 16 + lj;
  const bool rowok = row < n;
  const XT* xrow = X + (size_t)row * 128;

  f32x4 acc[8];
#pragma unroll
  for (int ct = 0; ct < 8; ++ct) acc[ct] = (f32x4){0.f, 0.f, 0.f, 0.f};

#pragma unroll
  for (int kt = 0; kt < 4; ++kt) {
    const int k0 = kt * 32 + lg * 8;
    float xv[8];
    load8(xrow + k0, xv, rowok);
    if (BN) {
#pragma unroll
      for (int b = 0; b < 8; ++b) xv[b] = selu_f(xv[b] * sc[k0 + b] + sh[k0 + b]);
    }
    short8 bx;
#pragma unroll
    for (int b = 0; b < 8; ++b) bx[b] = (short)f2bf(xv[b]);
#pragma unroll
    for (int ct = 0; ct < 8; ++ct) {
      short8 af = *(const short8*)(Wp + ((((ct * 4 + kt) * 4 + lg) * 16 + lj) << 3));
      acc[ct] = __builtin_amdgcn_mfma_f32_16x16x32_bf16(af, bx, acc[ct], 0, 0, 0);
    }
  }

  if (rowok) {
#pragma unroll
    for (int ct = 0; ct < 8; ++ct) {
      ushort4 h4;
      h4.x = f2bf(acc[ct][0]);
      h4.y = f2bf(acc[ct][1]);
      h4.z = f2bf(acc[ct][2]);
      h4.w = f2bf(acc[ct][3]);
      *(ushort4*)&H[(size_t)row * 128 + ct * 16 + lg * 4] = h4;
    }
  }

  if (HEADS == 8) {
    float ps[8], pd[8];
#pragma unroll
    for (int ct = 0; ct < 8; ++ct) {
      float4 av = *(const float4*)&asr[ct * 16 + lg * 4];
      float4 dv = *(const float4*)&adt[ct * 16 + lg * 4];
      ps[ct] = acc[ct][0] * av.x + acc[ct][1] * av.y + acc[ct][2] * av.z + acc[ct][3] * av.w;
      pd[ct] = acc[ct][0] * dv.x + acc[ct][1] * dv.y + acc[ct][2] * dv.z + acc[ct][3] * dv.w;
      ps[ct] += __shfl_xor(ps[ct], 16);
      ps[ct] += __shfl_xor(ps[ct], 32);
      pd[ct] += __shfl_xor(pd[ct], 16);
      pd[ct] += __shfl_xor(pd[ct], 32);
    }
    if (lg == 0 && rowok) {
      *(float4*)&ssrc[(size_t)row * 8] = make_float4(ps[0], ps[1], ps[2], ps[3]);
      *(float4*)&ssrc[(size_t)row * 8 + 4] = make_float4(ps[4], ps[5], ps[6], ps[7]);
      *(float4*)&sdst[(size_t)row * 8] = make_float4(pd[0], pd[1], pd[2], pd[3]);
      *(float4*)&sdst[(size_t)row * 8 + 4] = make_float4(pd[4], pd[5], pd[6], pd[7]);
    }
  } else {
    float ps = 0.f, pd = 0.f;
#pragma unroll
    for (int ct = 0; ct < 8; ++ct) {
      float4 av = *(const float4*)&asr[ct * 16 + lg * 4];
      float4 dv = *(const float4*)&adt[ct * 16 + lg * 4];
      ps += acc[ct][0] * av.x + acc[ct][1] * av.y + acc[ct][2] * av.z + acc[ct][3] * av.w;
      pd += acc[ct][0] * dv.x + acc[ct][1] * dv.y + acc[ct][2] * dv.z + acc[ct][3] * dv.w;
    }
    ps += __shfl_xor(ps, 16);
    ps += __shfl_xor(ps, 32);
    pd += __shfl_xor(pd, 16);
    pd += __shfl_xor(pd, 32);
    if (lg == 0 && rowok) {
      ssrc[row] = ps;
      sdst[row] = pd;
    }
  }
}

// ---------------- fused: GEMM1 (blocks < gb) + edge bucketing (blocks >= gb) ----------
__global__ __launch_bounds__(256) void gemm1_bucket_kernel(
    const float* __restrict__ X, const ushort* __restrict__ Wp, ushort* __restrict__ H,
    const float* __restrict__ asr, const float* __restrict__ adt,
    float* __restrict__ ssrc, float* __restrict__ sdst, int n,
    const int* __restrict__ ei, int* __restrict__ gcur, uint* __restrict__ bucket,
    int nE, int EA, int NB, int gb) {
  if (blockIdx.x < gb) {
    gemm_body<8, false, float>(blockIdx.x, X, Wp, H, asr, adt, ssrc, sdst, n,
                               nullptr, nullptr, nullptr);
    return;
  }
  __shared__ int lcnt[128];
  __shared__ int lbase[128];
  int tid = threadIdx.x;
  if (tid < 128) lcnt[tid] = 0;
  __syncthreads();
  int e0 = (blockIdx.x - gb) * 1024;
  uint ent[4];
  int bk[4], lp[4];
#pragma unroll
  for (int j = 0; j < 4; ++j) {
    int e = e0 + j * 256 + tid;
    bk[j] = -1;
    if (e < EA) {
      int src, dst;
      if (e < nE) {
        src = ei[e];
        dst = ei[nE + e];
      } else {
        src = dst = e - nE;
      }
      bk[j] = dst >> 9;
      ent[j] = ((uint)src << 9) | (uint)(dst & 511);
      lp[j] = atomicAdd(&lcnt[bk[j]], 1);
    }
  }
  __syncthreads();
  if (tid < NB && lcnt[tid] > 0) lbase[tid] = atomicAdd(&gcur[tid], lcnt[tid]);
  __syncthreads();
#pragma unroll
  for (int j = 0; j < 4; ++j) {
    if (bk[j] >= 0) bucket[(size_t)bk[j] * BCAP + lbase[bk[j]] + lp[j]] = ent[j];
  }
}

// ---------------- GEMM2 standalone (bf16 X, BN fused) ----------------
__global__ __launch_bounds__(256) void gemm2_kernel(
    const ushort* __restrict__ X, const ushort* __restrict__ Wp, ushort* __restrict__ H,
    const float* __restrict__ asr, const float* __restrict__ adt,
    float* __restrict__ ssrc, float* __restrict__ sdst, int n,
    const float* __restrict__ stats, const float* __restrict__ gamma,
    const float* __restrict__ beta) {
  gemm_body<1, true, ushort>(blockIdx.x, X, Wp, H, asr, adt, ssrc, sdst, n,
                             stats, gamma, beta);
}

// ---------------- CSR pass 2: per-bucket (512 nodes) degree + scan + fill ------------
__global__ __launch_bounds__(1024) void csrbuild_kernel(const int* __restrict__ gcur,
                                                        const uint* __restrict__ bucket,
                                                        int* __restrict__ offs,
                                                        int* __restrict__ csr,
                                                        int n, int NB) {
  __shared__ int ldeg[512];
  __shared__ int loff[512];
  __shared__ int lwsum[8];
  __shared__ int partial[2];
  int b = blockIdx.x, tid = threadIdx.x;
  int lane = tid & 63, w = tid >> 6;
  if (tid < 128) {
    int v = (tid < b) ? gcur[tid] : 0;
#pragma unroll
    for (int s = 1; s < 64; s <<= 1) v += __shfl_xor(v, s);
    if (lane == 0) partial[tid >> 6] = v;
  }
  if (tid < 512) ldeg[tid] = 0;
  __syncthreads();
  int base = partial[0] + partial[1];
  int cnt = gcur[b];
  const uint* bb = bucket + (size_t)b * BCAP;
  for (int k = tid; k < cnt; k += 1024) atomicAdd(&ldeg[bb[k] & 511], 1);
  __syncthreads();
  int v = 0, x = 0;
  if (tid < 512) {
    v = ldeg[tid];
    x = v;
#pragma unroll
    for (int s = 1; s < 64; s <<= 1) {
      int t = __shfl_up(x, s);
      if (lane >= s) x += t;
    }
    if (lane == 63) lwsum[w] = x;
  }
  __syncthreads();
  if (w == 0 && lane < 8) {
    int wv = lwsum[lane];
    int y = wv;
#pragma unroll
    for (int s = 1; s < 8; s <<= 1) {
      int t = __shfl_up(y, s);
      if (lane >= s) y += t;
    }
    lwsum[lane] = y - wv;  // exclusive
  }
  __syncthreads();
  if (tid < 512) {
    int excl = x - v + lwsum[w];
    loff[tid] = excl;
    int node = b * 512 + tid;
    if (node < n) offs[node] = base + excl;
  }
  if (b == NB - 1 && tid == 0) offs[n] = base + cnt;
  __syncthreads();
  if (tid < 512) ldeg[tid] = loff[tid];
  __syncthreads();
  for (int k = tid; k < cnt; k += 1024) {
    uint e = bb[k];
    int pos = atomicAdd(&ldeg[e & 511], 1);
    csr[base + pos] = (int)(e >> 9);
  }
}

// -------- agg layer 1: quarter-waves (16 lanes/quarter), 8 ch/lane, bf16 out ----------
// All accumulators NAMED SCALARS (R12: arrays spill). No fused stats (R12: atomic storm).
__global__ __launch_bounds__(256) void agg1_kernel(const ushort* __restrict__ h1,
                                                   const int* __restrict__ csr,
                                                   const int* __restrict__ offs,
                                                   const float* __restrict__ ssrc,
                                                   const float* __restrict__ sdst,
                                                   const float* __restrict__ bias,
                                                   ushort* __restrict__ outb, int nN) {
  int wid = (blockIdx.x * blockDim.x + threadIdx.x) >> 6;
  int lane = threadIdx.x & 63;
  int q = lane >> 4, ll = lane & 15;
  if (wid >= nN) return;
  int c = ll * 8;   // 8 channels per lane
  int h = ll >> 1;  // head = c/16
  float sd = sdst[wid * 8 + h];
  int beg = offs[wid];
  int deg = offs[wid + 1] - beg;
  float b0 = 0.f, b1 = 0.f, b2 = 0.f, b3 = 0.f;
  float b4 = 0.f, b5 = 0.f, b6 = 0.f, b7 = 0.f, den = 0.f;
  int i = q;
  for (; i + 4 < deg; i += 8) {
    int s0 = csr[beg + i];
    int s1 = csr[beg + i + 4];
    float e0 = ssrc[s0 * 8 + h];
    float e1 = ssrc[s1 * 8 + h];
    short8 u0 = *(const short8*)&h1[(size_t)s0 * 128 + c];
    short8 u1 = *(const short8*)&h1[(size_t)s1 * 128 + c];
    float A0 = __expf(leaky02(e0 + sd));
    float A1 = __expf(leaky02(e1 + sd));
    b0 += A0 * bf2f((ushort)u0[0]) + A1 * bf2f((ushort)u1[0]);
    b1 += A0 * bf2f((ushort)u0[1]) + A1 * bf2f((ushort)u1[1]);
    b2 += A0 * bf2f((ushort)u0[2]) + A1 * bf2f((ushort)u1[2]);
    b3 += A0 * bf2f((ushort)u0[3]) + A1 * bf2f((ushort)u1[3]);
    b4 += A0 * bf2f((ushort)u0[4]) + A1 * bf2f((ushort)u1[4]);
    b5 += A0 * bf2f((ushort)u0[5]) + A1 * bf2f((ushort)u1[5]);
    b6 += A0 * bf2f((ushort)u0[6]) + A1 * bf2f((ushort)u1[6]);
    b7 += A0 * bf2f((ushort)u0[7]) + A1 * bf2f((ushort)u1[7]);
    den += A0 + A1;
  }
  if (i < deg) {
    int s0 = csr[beg + i];
    float e0 = ssrc[s0 * 8 + h];
    short8 u0 = *(const short8*)&h1[(size_t)s0 * 128 + c];
    float A0 = __expf(leaky02(e0 + sd));
    b0 += A0 * bf2f((ushort)u0[0]);
    b1 += A0 * bf2f((ushort)u0[1]);
    b2 += A0 * bf2f((ushort)u0[2]);
    b3 += A0 * bf2f((ushort)u0[3]);
    b4 += A0 * bf2f((ushort)u0[4]);
    b5 += A0 * bf2f((ushort)u0[5]);
    b6 += A0 * bf2f((ushort)u0[6]);
    b7 += A0 * bf2f((ushort)u0[7]);
    den += A0;
  }
  b0 += __shfl_xor(b0, 16); b0 += __shfl_xor(b0, 32);
  b1 += __shfl_xor(b1, 16); b1 += __shfl_xor(b1, 32);
  b2 += __shfl_xor(b2, 16); b2 += __shfl_xor(b2, 32);
  b3 += __shfl_xor(b3, 16); b3 += __shfl_xor(b3, 32);
  b4 += __shfl_xor(b4, 16); b4 += __shfl_xor(b4, 32);
  b5 += __shfl_xor(b5, 16); b5 += __shfl_xor(b5, 32);
  b6 += __shfl_xor(b6, 16); b6 += __shfl_xor(b6, 32);
  b7 += __shfl_xor(b7, 16); b7 += __shfl_xor(b7, 32);
  den += __shfl_xor(den, 16); den += __shfl_xor(den, 32);
  if (q == 0) {
    float invd = 1.0f / (den + 1e-16f);
    float4 bv0 = *(const float4*)&bias[c];
    float4 bv1 = *(const float4*)&bias[c + 4];
    short8 o;
    o[0] = (short)f2bf(b0 * invd + bv0.x);
    o[1] = (short)f2bf(b1 * invd + bv0.y);
    o[2] = (short)f2bf(b2 * invd + bv0.z);
    o[3] = (short)f2bf(b3 * invd + bv0.w);
    o[4] = (short)f2bf(b4 * invd + bv1.x);
    o[5] = (short)f2bf(b5 * invd + bv1.y);
    o[6] = (short)f2bf(b6 * invd + bv1.z);
    o[7] = (short)f2bf(b7 * invd + bv1.w);
    *(short8*)&outb[(size_t)wid * 128 + c] = o;
  }
}

// -------- agg layer 2: quarter-waves, 8 ch/lane, bf16 out (pre-BN rounding) ----------
__global__ __launch_bounds__(256) void agg2_kernel(const ushort* __restrict__ h2,
                                                   const int* __restrict__ csr,
                                                   const int* __restrict__ offs,
                                                   const float* __restrict__ ssrc,
                                                   const float* __restrict__ sdst,
                                                   const float* __restrict__ bias,
                                                   ushort* __restrict__ outb, int nN) {
  int wid = (blockIdx.x * blockDim.x + threadIdx.x) >> 6;
  int lane = threadIdx.x & 63;
  int q = lane >> 4, ll = lane & 15;
  if (wid >= nN) return;
  int c = ll * 8;
  float sd = sdst[wid];
  int beg = offs[wid];
  int deg = offs[wid + 1] - beg;
  float b0 = 0.f, b1 = 0.f, b2 = 0.f, b3 = 0.f;
  float b4 = 0.f, b5 = 0.f, b6 = 0.f, b7 = 0.f, den = 0.f;
  int i = q;
  for (; i + 4 < deg; i += 8) {
    int s0 = csr[beg + i];
    int s1 = csr[beg + i + 4];
    float e0 = ssrc[s0];
    float e1 = ssrc[s1];
    short8 u0 = *(const short8*)&h2[(size_t)s0 * 128 + c];
    short8 u1 = *(const short8*)&h2[(size_t)s1 * 128 + c];
    float A0 = __expf(leaky02(e0 + sd));
    float A1 = __expf(leaky02(e1 + sd));
    b0 += A0 * bf2f((ushort)u0[0]) + A1 * bf2f((ushort)u1[0]);
    b1 += A0 * bf2f((ushort)u0[1]) + A1 * bf2f((ushort)u1[1]);
    b2 += A0 * bf2f((ushort)u0[2]) + A1 * bf2f((ushort)u1[2]);
    b3 += A0 * bf2f((ushort)u0[3]) + A1 * bf2f((ushort)u1[3]);
    b4 += A0 * bf2f((ushort)u0[4]) + A1 * bf2f((ushort)u1[4]);
    b5 += A0 * bf2f((ushort)u0[5]) + A1 * bf2f((ushort)u1[5]);
    b6 += A0 * bf2f((ushort)u0[6]) + A1 * bf2f((ushort)u1[6]);
    b7 += A0 * bf2f((ushort)u0[7]) + A1 * bf2f((ushort)u1[7]);
    den += A0 + A1;
  }
  if (i < deg) {
    int s0 = csr[beg + i];
    float e0 = ssrc[s0];
    short8 u0 = *(const short8*)&h2[(size_t)s0 * 128 + c];
    float A0 = __expf(leaky02(e0 + sd));
    b0 += A0 * bf2f((ushort)u0[0]);
    b1 += A0 * bf2f((ushort)u0[1]);
    b2 += A0 * bf2f((ushort)u0[2]);
    b3 += A0 * bf2f((ushort)u0[3]);
    b4 += A0 * bf2f((ushort)u0[4]);
    b5 += A0 * bf2f((ushort)u0[5]);
    b6 += A0 * bf2f((ushort)u0[6]);
    b7 += A0 * bf2f((ushort)u0[7]);
    den += A0;
  }
  b0 += __shfl_xor(b0, 16); b0 += __shfl_xor(b0, 32);
  b1 += __shfl_xor(b1, 16); b1 += __shfl_xor(b1, 32);
  b2 += __shfl_xor(b2, 16); b2 += __shfl_xor(b2, 32);
  b3 += __shfl_xor(b3, 16); b3 += __shfl_xor(b3, 32);
  b4 += __shfl_xor(b4, 16); b4 += __shfl_xor(b4, 32);
  b5 += __shfl_xor(b5, 16); b5 += __shfl_xor(b5, 32);
  b6 += __shfl_xor(b6, 16); b6 += __shfl_xor(b6, 32);
  b7 += __shfl_xor(b7, 16); b7 += __shfl_xor(b7, 32);
  den += __shfl_xor(den, 16); den += __shfl_xor(den, 32);
  if (q == 0) {
    float invd = 1.0f / (den + 1e-16f);
    float4 bv0 = *(const float4*)&bias[c];
    float4 bv1 = *(const float4*)&bias[c + 4];
    short8 o;
    o[0] = (short)f2bf(b0 * invd + bv0.x);
    o[1] = (short)f2bf(b1 * invd + bv0.y);
    o[2] = (short)f2bf(b2 * invd + bv0.z);
    o[3] = (short)f2bf(b3 * invd + bv0.w);
    o[4] = (short)f2bf(b4 * invd + bv1.x);
    o[5] = (short)f2bf(b5 * invd + bv1.y);
    o[6] = (short)f2bf(b6 * invd + bv1.z);
    o[7] = (short)f2bf(b7 * invd + bv1.w);
    *(short8*)&outb[(size_t)wid * 128 + c] = o;
  }
}

// ---------------- column stats (sum, sumsq): bf16 input ----------------
__global__ __launch_bounds__(256) void stats_bf16_kernel(const ushort* __restrict__ X,
                                                         float* __restrict__ stats, int n) {
  __shared__ float red[256];
  int tid = threadIdx.x;
  int c = tid & 127;
  int half = tid >> 7;
  float s = 0.f, sq = 0.f;
  int rbeg = (int)blockIdx.x * 64 + half;
  int rend = min((int)(blockIdx.x + 1) * 64, n);
#pragma unroll 4
  for (int r = rbeg; r < rend; r += 2) {
    float v = bf2f(X[(size_t)r * 128 + c]);
    s += v;
    sq += v * v;
  }
  red[tid] = s;
  __syncthreads();
  float s2 = (half == 0) ? s + red[tid + 128] : 0.f;
  __syncthreads();
  red[tid] = sq;
  __syncthreads();
  if (half == 0) {
    float sq2 = sq + red[tid + 128];
    atomicAdd(&stats[c], s2);
    atomicAdd(&stats[128 + c], sq2);
  }
}

// ---------------- BatchNorm (batch stats, biased var) + SELU: bf16 in, fp32 out -------
__global__ __launch_bounds__(256) void bnselu_bf16_kernel(const ushort* __restrict__ X,
                                                          const float* __restrict__ stats,
                                                          const float* __restrict__ gamma,
                                                          const float* __restrict__ beta,
                                                          float* __restrict__ Y, int n) {
  int gid = blockIdx.x * blockDim.x + threadIdx.x;
  if (gid >= n * 32) return;
  int c = (gid & 31) * 4;
  int r = gid >> 5;
  float invN = 1.0f / (float)n;
  ushort4 u = *(const ushort4*)&X[(size_t)r * 128 + c];
  float xv[4] = {bf2f(u.x), bf2f(u.y), bf2f(u.z), bf2f(u.w)};
  float o[4];
#pragma unroll
  for (int j = 0; j < 4; ++j) {
    float mu = stats[c + j] * invN;
    float var = stats[128 + c + j] * invN - mu * mu;
    float rs = rsqrtf(var + 1e-5f);
    float y = gamma[c + j] * ((xv[j] - mu) * rs) + beta[c + j];
    o[j] = selu_f(y);
  }
  *(float4*)&Y[(size_t)r * 128 + c] = make_float4(o[0], o[1], o[2], o[3]);
}

extern "C" void kernel_launch(void* const* d_in, const int* in_sizes, int n_in,
                              void* d_out, int out_size, void* d_ws, size_t ws_size,
                              hipStream_t stream) {
  const float* x   = (const float*)d_in[0];
  const int*   ei  = (const int*)d_in[1];
  // d_in[2] = edge_attr: unused (edge_dim=None)
  const float* W1  = (const float*)d_in[3];
  const float* as1 = (const float*)d_in[4];
  const float* ad1 = (const float*)d_in[5];
  const float* b1  = (const float*)d_in[6];
  const float* g1  = (const float*)d_in[7];
  const float* be1 = (const float*)d_in[8];
  const float* W2  = (const float*)d_in[9];
  const float* as2 = (const float*)d_in[10];
  const float* ad2 = (const float*)d_in[11];
  const float* b2  = (const float*)d_in[12];
  const float* g2  = (const float*)d_in[13];
  const float* be2 = (const float*)d_in[14];
  float* out = (float*)d_out;

  const int n  = in_sizes[0] / 128;   // 50000
  const int nE = in_sizes[1] / 2;     // 800000
  const int EA = nE + n;              // 850000
  const int NB = (n + 511) >> 9;      // 98 dst buckets (512 nodes each)
  const int nbb = (EA + 1023) / 1024; // bucket blocks
  const int gb = (n + 63) / 64;       // gemm blocks

  float* ws = (float*)d_ws;
  size_t o = 0;
  ushort* Bf = (ushort*)(ws + o); o += (size_t)n * 64;  // bf16: agg out / BN+gemm2 in
  ushort* H = (ushort*)(ws + o); o += (size_t)n * 64;   // bf16 h (gather table, reused)
  float* ssrc1 = ws + o;  o += (size_t)n * 8;
  float* sdst1 = ws + o;  o += (size_t)n * 8;
  float* ssrc2 = ws + o;  o += n;
  float* sdst2 = ws + o;  o += n;
  ushort* Wp1 = (ushort*)(ws + o); o += 8192;     // 16384 bf16
  ushort* Wp2 = (ushort*)(ws + o); o += 8192;
  // ---- zero region start ----
  float* zbase = ws + o;
  float* stats1 = ws + o; o += 256;
  float* stats2 = ws + o; o += 256;
  int* gcur = (int*)(ws + o); o += 128;
  int zwords = (int)((ws + o) - zbase);
  // ---- zero region end ----
  int* offs = (int*)(ws + o); o += (size_t)n + 1;
  int* csr  = (int*)(ws + o); o += EA;
  uint* bucket = (uint*)(ws + o); o += (size_t)NB * BCAP;

  // W pack + zero stats/gcur (block 128)
  pack_kernel<<<129, 256, 0, stream>>>(W1, W2, Wp1, Wp2, zbase, zwords);

  // ---- layer 1 GEMM (+ fused scores) overlapped with edge bucketing ----
  gemm1_bucket_kernel<<<gb + nbb, 256, 0, stream>>>(
      x, Wp1, H, as1, ad1, ssrc1, sdst1, n, ei, gcur, bucket, nE, EA, NB, gb);
  csrbuild_kernel<<<NB, 1024, 0, stream>>>(gcur, bucket, offs, csr, n, NB);

  agg1_kernel<<<(n + 3) / 4, 256, 0, stream>>>(H, csr, offs, ssrc1, sdst1, b1, Bf, n);
  stats_bf16_kernel<<<(n + 63) / 64, 256, 0, stream>>>(Bf, stats1, n);

  // ---- layer 2 (BN+SELU fused into GEMM2 X load; GEMM + fused scores) ----
  gemm2_kernel<<<gb, 256, 0, stream>>>(
      Bf, Wp2, H, as2, ad2, ssrc2, sdst2, n, stats1, g1, be1);
  agg2_kernel<<<(n + 3) / 4, 256, 0, stream>>>(H, csr, offs, ssrc2, sdst2, b2, Bf, n);
  stats_bf16_kernel<<<(n + 63) / 64, 256, 0, stream>>>(Bf, stats2, n);
  bnselu_bf16_kernel<<<(n * 32 + 255) / 256, 256, 0, stream>>>(Bf, stats2, g2, be2, out, n);
}